// Round 8
// baseline (325.038 us; speedup 1.0000x reference)
//
#include <hip/hip_runtime.h>

// NeuralSumProductModel: weighted sum-product LDPC decoder.
// N=8192 vars, M=4096 checks, DV=3, DC=6, ITERS=5, B=1024, E=24576.
// One block per batch row; thread t owns 24 contiguous edges = 8 variables
// (variable side) and 4 checks (check side).
//
// R11 change vs R10 (157 µs, SQ_LDS_BANK_CONFLICT 2.0e7 = ~21% of cycles):
// BANK-AWARE SLOT MATCHING. The hot kernel is byte-identical to R10; only
// the setup changes. The random var-side LDS ops execute in fixed 64-lane
// instruction groups g=(wave, e-index) (same grouping for Phase A reads,
// Phase A writes, it==0 writes, final gather). Bank of edge e is
// (7c+slot)%32: the bank SET per check is fixed, but WHICH edge gets which
// bank is a free 6-way matching per check. Old setup assigned slots by
// atomicAdd arrival = random banks (measured ~18 extra cycles per random
// wave-op, near worst-case). New setup: greedy matching — each check gives
// each of its 6 edges the least-loaded bank of that edge's group
// (LDS counter table gcnt[384][32], LDS atomics; races -> stale counts,
// quality still ~greedy). Any bijective slot assignment is algebraically
// valid; only f32 product order shifts by ulps.
//
// Carried: R9 one-wait batched phases; R8 tanh domain (4 trans/edge/iter,
// prefix/suffix LOO products); R7 merged A2B (check-owner computes r in
// place); CSTRIDE=7 (gcd(7,32)=1) conflict-free structured side.

#define N_VARS 8192
#define M_CHK  4096
#define ITERS  5
#define BATCH  1024
#define NEDGE  (N_VARS * 3)     // 24576
#define TPB    1024
#define EPT    (NEDGE / TPB)    // 24 edges / thread
#define VPT    (N_VARS / TPB)   // 8 variables / thread
#define CPT    (M_CHK / TPB)    // 4 checks / thread
#define CSTRIDE 7               // padded check stride: conflict-free stride-7
#define NGRP   (16 * 24)        // (waves/block) x (e-indices) = 384 groups

#define LOG2E_F 1.44269504f
#define LN2_F   0.69314718f
#define E_CLIP  0.99999988f     // float32(1 - 1e-7)

// t = tanh(x/2), sign carried in the float itself
__device__ __forceinline__ float tanh_half(float x) {
    float a  = fabsf(x);
    float ee = __builtin_amdgcn_exp2f(-a * LOG2E_F);     // e^{-|x|}
    float tt = (1.0f - ee) * __builtin_amdgcn_rcpf(1.0f + ee);
    unsigned sg = __float_as_uint(x) & 0x80000000u;
    return __uint_as_float(__float_as_uint(tt) | sg);
}

// r = 2*atanh(clamp(p)) ; p in [-1,1]
__device__ __forceinline__ float atanh2(float p) {
    p = fminf(fmaxf(p, -E_CLIP), E_CLIP);                // med3 clamp
    return LN2_F * (__builtin_amdgcn_logf(1.0f + p)
                  - __builtin_amdgcn_logf(1.0f - p));    // log2 pair
}

// ---- setup pass 1: check -> edge lists (rank by atomicAdd arrival)
__global__ void build_ce(const int* __restrict__ chk,
                         int* __restrict__ ce,
                         int* __restrict__ cnt) {
    int e = blockIdx.x * 256 + threadIdx.x;
    if (e < NEDGE) {
        int c = chk[e];
        int r = atomicAdd(&cnt[c], 1);
        ce[c * 6 + r] = e;
    }
}

// ---- setup pass 2 (single block): greedy bank matching.
// Edge e belongs to instruction group g = (owner_wave)*24 + e_idx where
// owner thread t = e/24, owner_wave = t/64, e_idx = e%24. For each check,
// assign its 6 edges to the 6 slots so each edge lands on the currently
// least-loaded bank of its group. Banks: (c*7+slot) & 31.
__global__ __launch_bounds__(1024)
void assign_slots(const int* __restrict__ ce,
                  unsigned* __restrict__ tbl) {
    __shared__ unsigned gcnt[NGRP * 32];    // 48 KB group-bank load table
    const int tid = threadIdx.x;
    for (int i = tid; i < NGRP * 32; i += 1024)
        gcnt[i] = 0;
    __syncthreads();
#pragma unroll
    for (int k = 0; k < M_CHK / 1024; ++k) {
        const int c = tid + k * 1024;
        const int cbase = c * CSTRIDE;
        unsigned avail = 0x3Fu;             // slots 0..5 free
        for (int r = 0; r < 6; ++r) {
            int e = ce[c * 6 + r];
            int t = e / 24;                 // owner thread in block
            int g = (t >> 6) * 24 + (e - t * 24);
            // pick available slot whose bank is least loaded in group g
            int best = -1;
            unsigned bestc = ~0u;
#pragma unroll
            for (int s = 0; s < 6; ++s) {
                if ((avail >> s) & 1u) {
                    unsigned cc = gcnt[g * 32 + ((cbase + s) & 31)];
                    if (cc < bestc) { bestc = cc; best = s; }
                }
            }
            atomicAdd(&gcnt[g * 32 + ((cbase + best) & 31)], 1u);
            avail &= ~(1u << best);
            tbl[e] = (unsigned)(cbase + best);   // < 28672, fits 16 bits
        }
    }
}

__global__ void __launch_bounds__(TPB, 4)
nsp_kernel(const float* __restrict__ llr,
           const float* __restrict__ vw,
           const float* __restrict__ cw,
           const unsigned* __restrict__ tbl,
           float* __restrict__ out)
{
    __shared__ float lds_m[M_CHK * CSTRIDE];  // 112 KB: per-edge state at
                                              // c*7+slot. Phase A leaves
                                              // t=tanh(x/2) here; A2B leaves
                                              // the signed check msg r here.

    const int b  = blockIdx.x;
    const int t  = threadIdx.x;
    const int e0 = t * EPT;
    const int n0 = t * VPT;

    // llr for my 8 variables
    float llr_v[VPT];
    {
        const float4* p = (const float4*)(llr + (size_t)b * N_VARS + n0);
        float4 a = p[0], c = p[1];
        llr_v[0] = a.x; llr_v[1] = a.y; llr_v[2] = a.z; llr_v[3] = a.w;
        llr_v[4] = c.x; llr_v[5] = c.y; llr_v[6] = c.z; llr_v[7] = c.w;
    }

    // 16-bit LDS addrs for my 24 edges, packed 2/reg (12 VGPRs)
    unsigned pa[EPT / 2];
    {
        const uint4* p = (const uint4*)(tbl + e0);
#pragma unroll
        for (int k = 0; k < EPT / 4; ++k) {
            uint4 v = p[k];
            pa[2 * k]     = v.x | (v.y << 16);
            pa[2 * k + 1] = v.z | (v.w << 16);
        }
    }
#define ADDR(e) ((pa[(e) >> 1] >> (((e) & 1) * 16)) & 0xFFFFu)

    // 4-var compute chunk (v0 literal -> all indices compile-time const).
    // rr = the 24 batched random r-reads (done by caller, one wait).
    auto computeA4 = [&](int v0, const float* cwr, const float* vwr,
                         float* op, const float* rr) {
        float outb[4];
#pragma unroll
        for (int vv = 0; vv < 4; ++vv) {
            const int v = v0 + vv;
            float x0 = rr[3 * v + 0] * cwr[3 * v + 0];
            float x1 = rr[3 * v + 1] * cwr[3 * v + 1];
            float x2 = rr[3 * v + 2] * cwr[3 * v + 2];
            float s  = x0 + x1 + x2;
            outb[vv] = s + llr_v[v];            // output row it-1 (fused)
#pragma unroll
            for (int j = 0; j < 3; ++j) {
                const int e = 3 * v + j;
                float extj = (j == 0) ? x0 : (j == 1) ? x1 : x2;
                float x = (s - extj) * vwr[e] + llr_v[v];
                lds_m[ADDR(e)] = tanh_half(x);  // own slot: no hazard
            }
        }
        *((float4*)(op + v0)) = make_float4(outb[0], outb[1], outb[2], outb[3]);
    };

    for (int it = 0; it < ITERS; ++it) {
        // ---- Phase A: variable-node LOO, store t = tanh(x/2) per edge.
        if (it == 0) {
#pragma unroll
            for (int v = 0; v < VPT; ++v) {
                float p = tanh_half(llr_v[v]);  // ext==0: same t on 3 edges
#pragma unroll
                for (int j = 0; j < 3; ++j)
                    lds_m[ADDR(3 * v + j)] = p;
            }
        } else {
            const float* cwr = cw + (size_t)(it - 1) * NEDGE + e0;
            const float* vwr = vw + (size_t)it * NEDGE + e0;
            float* op = out + ((size_t)(it - 1) * BATCH + b) * N_VARS + n0;
            // batch ALL 24 random reads: one lgkmcnt region
            float rr[EPT];
#pragma unroll
            for (int e = 0; e < EPT; ++e)
                rr[e] = lds_m[ADDR(e)];
            computeA4(0, cwr, vwr, op, rr);
            computeA4(4, cwr, vwr, op, rr);
        }
        __syncthreads();   // barrier 1: all t visible to check owners

        // ---- Phase A2B: leave-one-out product via prefix/suffix (12
        // mults, sign rides along) + 2*atanh, written back in place.
        // c = t + k*1024 -> lane stride 7 words, gcd(7,32)=1: reads AND
        // writes conflict-free. ALL 24 reads batched (one wait), then 4
        // independent check chains back-to-back for trans-pipe ILP.
        {
            float tv[CPT][6];
#pragma unroll
            for (int k = 0; k < CPT; ++k) {
                const int base = (t + k * TPB) * CSTRIDE;
#pragma unroll
                for (int i = 0; i < 6; ++i)
                    tv[k][i] = lds_m[base + i];
            }
#pragma unroll
            for (int k = 0; k < CPT; ++k) {
                const int base = (t + k * TPB) * CSTRIDE;
                float t0 = tv[k][0], t1 = tv[k][1], t2 = tv[k][2];
                float t3 = tv[k][3], t4 = tv[k][4], t5 = tv[k][5];
                // prefix products
                float p1 = t0 * t1;
                float p2 = p1 * t2;
                float p3 = p2 * t3;
                float p4 = p3 * t4;
                // suffix products
                float s4 = t5 * t4;
                float s3 = s4 * t3;
                float s2 = s3 * t2;
                float s1 = s2 * t1;
                lds_m[base + 0] = atanh2(s1);        // t1*t2*t3*t4*t5
                lds_m[base + 1] = atanh2(t0 * s2);
                lds_m[base + 2] = atanh2(p1 * s3);
                lds_m[base + 3] = atanh2(p2 * s4);
                lds_m[base + 4] = atanh2(p3 * t5);
                lds_m[base + 5] = atanh2(p4);        // t0*t1*t2*t3*t4
            }
        }
        __syncthreads();   // barrier 2: all r visible to edge owners
    }

    // ---- final output row: ext = r * cnode_w[ITERS-1]; 24 random reads
    // batched, then compute.
    {
        const float* cwr = cw + (size_t)(ITERS - 1) * NEDGE + e0;
        float* op = out + ((size_t)(ITERS - 1) * BATCH + b) * N_VARS + n0;
        float rr[EPT];
#pragma unroll
        for (int e = 0; e < EPT; ++e)
            rr[e] = lds_m[ADDR(e)];
        float outb[VPT];
#pragma unroll
        for (int v = 0; v < VPT; ++v) {
            outb[v] = rr[3 * v + 0] * cwr[3 * v + 0]
                    + rr[3 * v + 1] * cwr[3 * v + 1]
                    + rr[3 * v + 2] * cwr[3 * v + 2]
                    + llr_v[v];
        }
        ((float4*)op)[0] = make_float4(outb[0], outb[1], outb[2], outb[3]);
        ((float4*)op)[1] = make_float4(outb[4], outb[5], outb[6], outb[7]);
    }
#undef ADDR
}

extern "C" void kernel_launch(void* const* d_in, const int* in_sizes, int n_in,
                              void* d_out, int out_size, void* d_ws, size_t ws_size,
                              hipStream_t stream) {
    const float* llr = (const float*)d_in[0];   // (B, N)
    const float* vw  = (const float*)d_in[1];   // (ITERS, E)
    const float* cw  = (const float*)d_in[2];   // (ITERS, E)
    // d_in[3] = var_idx (unused: edges are variable-major, var = e/3)
    const int*   chk = (const int*)d_in[4];     // (E,)
    float* out = (float*)d_out;                 // (ITERS, B, N) f32

    // ws layout: [0,96K) u32 tbl[NEDGE]; [96K,112K) int cnt[M_CHK];
    //            [112K,208K) int ce[M_CHK*6]
    unsigned* tbl = (unsigned*)d_ws;
    int*      cnt = (int*)((char*)d_ws + NEDGE * sizeof(unsigned));
    int*      ce  = (int*)((char*)d_ws + NEDGE * sizeof(unsigned)
                                       + M_CHK * sizeof(int));

    hipMemsetAsync(cnt, 0, M_CHK * sizeof(int), stream);
    build_ce<<<(NEDGE + 255) / 256, 256, 0, stream>>>(chk, ce, cnt);
    assign_slots<<<1, 1024, 0, stream>>>(ce, tbl);
    nsp_kernel<<<BATCH, TPB, 0, stream>>>(llr, vw, cw, tbl, out);
}